// Round 11
// baseline (347.051 us; speedup 1.0000x reference)
//
#include <hip/hip_runtime.h>
#include <cmath>

#define HN 1024
#define NCH 12
#define AS 528                         // Ah column stride (513 used + pad); 4224 B rows
#define PI2 6.28318530717958647692f

// ---------- complex helpers ----------
__device__ __forceinline__ float2 cmul(float2 a, float2 b) {
  return make_float2(a.x * b.x - a.y * b.y, a.x * b.y + a.y * b.x);
}

// reverse 5 base-4 digits of a 10-bit index (involution)
__device__ __forceinline__ int drev(int k) {
  int r = 0;
#pragma unroll
  for (int i = 0; i < 5; ++i) { r = (r << 2) | (k & 3); k >>= 2; }
  return r;
}

// row-kernel LDS swizzle: pad every 16 elements
#define RIDX(h) ((h) + ((h) >> 4))
// padded twiddle index
#define TIDX(i) ((i) + ((i) >> 4))
// column-exchange buffer: 512 rows x 16 cols, stride 17
#define EIDX(h, c) ((h) * 17 + (c))

// ---------- radix-4 DIF butterfly (row kernels, unpadded tw) ----------
template <bool INV>
__device__ __forceinline__ void bf4(float2& a0, float2& a1, float2& a2, float2& a3,
                                    const float2* tw, int e) {
  float2 t0 = make_float2(a0.x + a2.x, a0.y + a2.y);
  float2 t1 = make_float2(a0.x - a2.x, a0.y - a2.y);
  float2 t2 = make_float2(a1.x + a3.x, a1.y + a3.y);
  float2 t3 = make_float2(a1.x - a3.x, a1.y - a3.y);
  float2 b0 = make_float2(t0.x + t2.x, t0.y + t2.y);
  float2 b2 = make_float2(t0.x - t2.x, t0.y - t2.y);
  float2 b1, b3;
  if (!INV) {
    b1 = make_float2(t1.x + t3.y, t1.y - t3.x);
    b3 = make_float2(t1.x - t3.y, t1.y + t3.x);
  } else {
    b1 = make_float2(t1.x - t3.y, t1.y + t3.x);
    b3 = make_float2(t1.x + t3.y, t1.y - t3.x);
  }
  float2 w1 = tw[e], w2 = tw[2 * e], w3 = tw[3 * e];
  if (INV) { w1.y = -w1.y; w2.y = -w2.y; w3.y = -w3.y; }
  a0 = b0;
  a1 = cmul(b1, w1);
  a2 = cmul(b2, w2);
  a3 = cmul(b3, w3);
}

// ---------- radix-4 DIF butterfly (column kernels, TIDX-padded tw) ----------
template <bool INV>
__device__ __forceinline__ void bf4t(float2& a0, float2& a1, float2& a2, float2& a3,
                                     const float2* tw, int e) {
  float2 t0 = make_float2(a0.x + a2.x, a0.y + a2.y);
  float2 t1 = make_float2(a0.x - a2.x, a0.y - a2.y);
  float2 t2 = make_float2(a1.x + a3.x, a1.y + a3.y);
  float2 t3 = make_float2(a1.x - a3.x, a1.y - a3.y);
  float2 b0 = make_float2(t0.x + t2.x, t0.y + t2.y);
  float2 b2 = make_float2(t0.x - t2.x, t0.y - t2.y);
  float2 b1, b3;
  if (!INV) {
    b1 = make_float2(t1.x + t3.y, t1.y - t3.x);
    b3 = make_float2(t1.x - t3.y, t1.y + t3.x);
  } else {
    b1 = make_float2(t1.x - t3.y, t1.y + t3.x);
    b3 = make_float2(t1.x + t3.y, t1.y - t3.x);
  }
  float2 w1 = tw[TIDX(e)], w2 = tw[TIDX(2 * e)], w3 = tw[TIDX(3 * e)];
  if (INV) { w1.y = -w1.y; w2.y = -w2.y; w3.y = -w3.y; }
  a0 = b0;
  a1 = cmul(b1, w1);
  a2 = cmul(b2, w2);
  a3 = cmul(b3, w3);
}

__device__ __forceinline__ void tw_init(float2* tw, int t, int nthr) {
  for (int i = t; i < 768; i += nthr) {
    float s, c;
    sincosf((float)i * (PI2 / 1024.f), &s, &c);
    tw[i] = make_float2(c, -s);
  }
}

__device__ __forceinline__ void tw_init_p(float2* tw, int t, int nthr) {
  for (int i = t; i < 768; i += nthr) {
    float s, c;
    sincosf((float)i * (PI2 / 1024.f), &s, &c);
    tw[TIDX(i)] = make_float2(c, -s);
  }
}

// 1024-pt radix-4 DIF FFT, one row per block, 256 threads.
template <bool INV>
__device__ __forceinline__ void fft_row(float2* x, const float2* tw, int t) {
#pragma unroll
  for (int ld = 8; ld >= 0; ld -= 2) {
    __syncthreads();
    const int d = 1 << ld;
    int j = t & (d - 1);
    int p0 = ((t >> ld) << (ld + 2)) | j;
    float2 a0 = x[RIDX(p0)];
    float2 a1 = x[RIDX(p0 + d)];
    float2 a2 = x[RIDX(p0 + 2 * d)];
    float2 a3 = x[RIDX(p0 + 3 * d)];
    bf4<INV>(a0, a1, a2, a3, tw, j << (8 - ld));
    x[RIDX(p0)] = a0;
    x[RIDX(p0 + d)] = a1;
    x[RIDX(p0 + 2 * d)] = a2;
    x[RIDX(p0 + 3 * d)] = a3;
  }
  __syncthreads();
}

// ---------------------------------------------------------------------------
// Register-resident 1024-pt column FFT (16 cols/block, 1024 thr) — verified.
// ---------------------------------------------------------------------------
template <bool INV>
__device__ __forceinline__ void colfft16(float2 (&r)[16], float2 (&q)[16],
                                         float2* ex, const float2* tw,
                                         int u, int c) {
  const int j2 = u & 3, B = u >> 2;
#pragma unroll
  for (int s = 0; s < 4; ++s)
    bf4t<INV>(r[s], r[s + 4], r[s + 8], r[s + 12], tw, u + (s << 6));
#pragma unroll
  for (int g = 0; g < 4; ++g)
    bf4t<INV>(r[4 * g], r[4 * g + 1], r[4 * g + 2], r[4 * g + 3], tw, u << 2);
#pragma unroll
  for (int it = 0; it < 8; ++it)
    ex[EIDX(u + (it << 6), c)] = r[it];
  __syncthreads();
  if (u < 32) {
#pragma unroll
    for (int m = 0; m < 16; ++m) {
      int hl = (B << 6) + j2 + ((m & 3) << 2) + ((m >> 2) << 4);
      q[m] = ex[EIDX(hl, c)];
    }
  }
  __syncthreads();
#pragma unroll
  for (int it = 8; it < 16; ++it)
    ex[EIDX(u + (it << 6) - 512, c)] = r[it];
  __syncthreads();
  if (u >= 32) {
#pragma unroll
    for (int m = 0; m < 16; ++m) {
      int hl = ((B - 8) << 6) + j2 + ((m & 3) << 2) + ((m >> 2) << 4);
      q[m] = ex[EIDX(hl, c)];
    }
  }
#pragma unroll
  for (int a = 0; a < 4; ++a)
    bf4t<INV>(q[a], q[4 + a], q[8 + a], q[12 + a], tw, (j2 + 4 * a) << 4);
#pragma unroll
  for (int b_ = 0; b_ < 4; ++b_)
    bf4t<INV>(q[4 * b_], q[4 * b_ + 1], q[4 * b_ + 2], q[4 * b_ + 3], tw, j2 << 6);
#pragma unroll
  for (int m = 0; m < 16; ++m) {
    float2 v = q[m];
    float2 p;
    p.x = __shfl_xor(v.x, 32);
    p.y = __shfl_xor(v.y, 32);
    float2 w;
    if (j2 & 2) { w.x = p.x - v.x; w.y = p.y - v.y; }
    else        { w.x = v.x + p.x; w.y = v.y + p.y; }
    float2 p2;
    p2.x = __shfl_xor(w.x, 16);
    p2.y = __shfl_xor(w.y, 16);
    float2 o;
    if (j2 == 0)      { o = make_float2(w.x + p2.x, w.y + p2.y); }
    else if (j2 == 1) { o = make_float2(p2.x - w.x, p2.y - w.y); }
    else if (j2 == 2) { o = INV ? make_float2(w.x - p2.y, w.y + p2.x)
                                : make_float2(w.x + p2.y, w.y - p2.x); }
    else              { o = INV ? make_float2(p2.x + w.y, p2.y - w.x)
                                : make_float2(p2.x - w.y, p2.y + w.x); }
    q[m] = o;
  }
}

// ---------------- K1: row FFT of alpha*z -> Ah (store k=0..512 only) ----------------
__global__ __launch_bounds__(256) void k1_rowfft(const float* __restrict__ z,
                                                 const float* __restrict__ alpha,
                                                 float2* __restrict__ Ah) {
  __shared__ float2 x[1088];
  __shared__ float2 tw[768];
  const int t = threadIdx.x;
  const int row = blockIdx.x, nc = blockIdx.y;
  tw_init(tw, t, 256);
  const float al = alpha[nc / 3];
  const float4* zr4 = (const float4*)(z + ((size_t)nc * HN + row) * HN);
  {
    float4 v = zr4[t];
    int h = t << 2;
    x[RIDX(h + 0)] = make_float2(v.x * al, 0.f);
    x[RIDX(h + 1)] = make_float2(v.y * al, 0.f);
    x[RIDX(h + 2)] = make_float2(v.z * al, 0.f);
    x[RIDX(h + 3)] = make_float2(v.w * al, 0.f);
  }
  fft_row<false>(x, tw, t);
  float2* Ar = Ah + ((size_t)nc * HN + row) * AS;
  float4* Ar4 = (float4*)Ar;
  {
    int k0 = t << 1;                       // pairs cover k = 0..511
    float2 a = x[RIDX(drev(k0))];
    float2 b = x[RIDX(drev(k0 | 1))];
    Ar4[t] = make_float4(a.x, a.y, b.x, b.y);
  }
  if (t == 0) Ar[512] = x[RIDX(drev(512))];
}

// ---------------- K2: col FFT in-place on Ah (513 cols; G = fft2(alpha z)) ----------------
__global__ __launch_bounds__(1024, 4) void k2_colfft(float2* __restrict__ Ah) {
  __shared__ float2 ex[8704];
  __shared__ float2 tw[816];
  const int t = threadIdx.x;
  const int c = t & 15, u = t >> 4;
  const int w0 = blockIdx.x << 4;          // 0..512 (block 32: col 512 + junk pad)
  const int nc = blockIdx.y;
  const size_t rb = (size_t)nc * HN;
  float2 r[16], q[16];
#pragma unroll
  for (int it = 0; it < 16; ++it) {
    int h = u + (it << 6);
    r[it] = Ah[(rb + h) * AS + w0 + c];
  }
  tw_init_p(tw, t, 1024);
  __syncthreads();
  colfft16<false>(r, q, ex, tw, u, c);
  const int j2 = u & 3, B = u >> 2;
  const int f = ((j2 & 1) << 1) | (j2 >> 1);
#pragma unroll
  for (int m = 0; m < 16; ++m) {
    int k = (f << 8) | ((m & 3) << 6) | ((m >> 2) << 4) | ((B & 3) << 2) | (B >> 2);
    Ah[(rb + k) * AS + w0 + c] = q[m];
  }
}

// ---------------- K3: FBR = blockmean(Fk*(G+FkCFy)) via Hermitian G; invW; divide ----------------
__global__ __launch_bounds__(256) void k3_reduce(const float2* __restrict__ Ah,
                                                 const float2* __restrict__ Fk,
                                                 const float2* __restrict__ FkCFy,
                                                 const float2* __restrict__ F2k,
                                                 const float* __restrict__ alpha,
                                                 float2* __restrict__ iw) {
  int idx = blockIdx.x * 256 + threadIdx.x;
  int j = idx & 255, i = (idx >> 8) & 255, nc = idx >> 16;
  size_t base = (size_t)nc * HN * HN;
  size_t rb = (size_t)nc * HN;
  float sx = 0.f, sy = 0.f, wx = 0.f, wy = 0.f;
#pragma unroll
  for (int s1 = 0; s1 < 4; ++s1) {
    int h = (s1 << 8) + i;
    int h2 = (1024 - h) & 1023;
#pragma unroll
    for (int s2 = 0; s2 < 4; ++s2) {
      int w = (s2 << 8) + j;
      size_t gi = base + (size_t)h * HN + w;
      float2 fk = Fk[gi];
      float2 fy = FkCFy[gi];
      float2 f2 = F2k[gi];
      bool mir = (w > 512);
      int col = mir ? 1024 - w : w;
      int row = mir ? h2 : h;
      float2 g = Ah[(rb + row) * AS + col];
      if (mir) g.y = -g.y;                 // conj
      float2 fr = make_float2(fy.x + g.x, fy.y + g.y);
      sx += fk.x * fr.x - fk.y * fr.y;
      sy += fk.x * fr.y + fk.y * fr.x;
      wx += f2.x;
      wy += f2.y;
    }
  }
  const float al = alpha[nc / 3];
  float dx = wx * 0.0625f + al, dy = wy * 0.0625f;   // invW + alpha (real part)
  float nx = sx * 0.0625f, ny = sy * 0.0625f;        // FBR
  float inv = 1.0f / (dx * dx + dy * dy);
  iw[idx] = make_float2((nx * dx + ny * dy) * inv, (ny * dx - nx * dy) * inv);
}

// ---------------- K4: Yh = Herm((FkCFy - FkC*invWBR)/alpha); inverse col FFT -> Ah ----------------
__global__ __launch_bounds__(1024, 4) void k4_colifft(float2* __restrict__ Ah,
                                                      const float2* __restrict__ FkCFy,
                                                      const float2* __restrict__ FkC,
                                                      const float2* __restrict__ iw,
                                                      const float* __restrict__ alpha) {
  __shared__ float2 ex[8704];
  __shared__ float2 tw[816];
  const int t = threadIdx.x;
  const int c = t & 15, u = t >> 4;
  const int w0 = blockIdx.x << 4;
  const int nc = blockIdx.y;
  const float ra = 0.5f / alpha[nc / 3];   // fold the Hermitian 1/2 into 1/alpha
  const size_t base = (size_t)nc * HN * HN;
  const size_t rb = (size_t)nc * HN;
  const int k = w0 + c;                    // 0..527 (>512 lanes compute junk, never read)
  const int kc = (1024 - k) & 1023;        // mirror column
  const float2* iwp = iw + ((size_t)nc << 16);
  const int jd = k & 255, jm = kc & 255;
  float2 r[16], q[16];
#pragma unroll
  for (int it = 0; it < 16; ++it) {
    int h = u + (it << 6);
    int h2 = (1024 - h) & 1023;
    // direct Y(h,k)
    size_t gd = base + (size_t)h * HN + k;
    float2 fy = FkCFy[gd];
    float2 fc = FkC[gd];
    float2 wd = iwp[((h & 255) << 8) | jd];
    float2 pd = cmul(fc, wd);
    // mirror Y(-h,-k)
    size_t gm = base + (size_t)h2 * HN + kc;
    float2 fym = FkCFy[gm];
    float2 fcm = FkC[gm];
    float2 wm = iwp[((h2 & 255) << 8) | jm];
    float2 pm = cmul(fcm, wm);
    // Yh = ((Yd) + conj(Ym)) * 0.5 / alpha
    r[it] = make_float2((fy.x - pd.x + fym.x - pm.x) * ra,
                        (fy.y - pd.y - fym.y + pm.y) * ra);
  }
  tw_init_p(tw, t, 1024);
  __syncthreads();
  colfft16<true>(r, q, ex, tw, u, c);
  const int j2 = u & 3, B = u >> 2;
  const int f = ((j2 & 1) << 1) | (j2 >> 1);
#pragma unroll
  for (int m = 0; m < 16; ++m) {
    int kr = (f << 8) | ((m & 3) << 6) | ((m >> 2) << 4) | ((B & 3) << 2) | (B >> 2);
    Ah[(rb + kr) * AS + k] = q[m];
  }
}

// ---------------- K5: Hermitian row rebuild + inverse row FFT; out = z + real*sc ----------------
__global__ __launch_bounds__(256) void k5_rowifft(const float2* __restrict__ Ah,
                                                  const float* __restrict__ z,
                                                  float* __restrict__ out) {
  __shared__ float2 x[1088];
  __shared__ float2 tw[768];
  const int t = threadIdx.x;
  const int row = blockIdx.x, nc = blockIdx.y;
  tw_init(tw, t, 256);
  const float2* Ar = Ah + ((size_t)nc * HN + row) * AS;
  const float4* Ar4 = (const float4*)Ar;
  {
    float4 v = Ar4[t];                     // k = 2t, 2t+1
    int k0 = t << 1;
    x[RIDX(k0)] = make_float2(v.x, v.y);
    x[RIDX(k0 | 1)] = make_float2(v.z, v.w);
  }
  if (t == 0) x[RIDX(512)] = Ar[512];
  __syncthreads();
  // Hermitian completion: k = 513..1023 : x[k] = conj(x[1024-k])
  {
    int k = 513 + t;                       // 513..768
    float2 g = x[RIDX(1024 - k)];
    x[RIDX(k)] = make_float2(g.x, -g.y);
  }
  if (t < 255) {
    int k = 769 + t;                       // 769..1023
    float2 g = x[RIDX(1024 - k)];
    x[RIDX(k)] = make_float2(g.x, -g.y);
  }
  fft_row<true>(x, tw, t);                 // starts with __syncthreads
  const float4* zr4 = (const float4*)(z + ((size_t)nc * HN + row) * HN);
  float4* outr4 = (float4*)(out + ((size_t)nc * HN + row) * HN);
  const float sc = 1.0f / (1024.0f * 1024.0f);
  {
    float4 zv = zr4[t];
    int k = t << 2;
    float4 o;
    o.x = x[RIDX(drev(k + 0))].x * sc + zv.x;
    o.y = x[RIDX(drev(k + 1))].x * sc + zv.y;
    o.z = x[RIDX(drev(k + 2))].x * sc + zv.z;
    o.w = x[RIDX(drev(k + 3))].x * sc + zv.w;
    outr4[t] = o;
  }
}

extern "C" void kernel_launch(void* const* d_in, const int* in_sizes, int n_in,
                              void* d_out, int out_size, void* d_ws, size_t ws_size,
                              hipStream_t stream) {
  const float*  z      = (const float*)d_in[0];
  const float2* Fk     = (const float2*)d_in[1];
  const float2* FkC    = (const float2*)d_in[2];
  const float2* F2k    = (const float2*)d_in[3];
  const float2* FkCFy  = (const float2*)d_in[4];
  const float*  alpha  = (const float*)d_in[5];
  (void)in_sizes; (void)n_in; (void)out_size; (void)ws_size;

  // workspace: Ah = 12 x 1024 x 528 complex (51.9 MB) | iw 6 MB
  float2* Ah = (float2*)d_ws;
  float2* iw = Ah + (size_t)NCH * HN * AS;
  float*  out = (float*)d_out;

  k1_rowfft<<<dim3(HN, NCH), dim3(256), 0, stream>>>(z, alpha, Ah);
  k2_colfft<<<dim3(33, NCH), dim3(1024), 0, stream>>>(Ah);
  k3_reduce<<<dim3(NCH * 256), dim3(256), 0, stream>>>(Ah, Fk, FkCFy, F2k, alpha, iw);
  k4_colifft<<<dim3(33, NCH), dim3(1024), 0, stream>>>(Ah, FkCFy, FkC, iw, alpha);
  k5_rowifft<<<dim3(HN, NCH), dim3(256), 0, stream>>>(Ah, z, out);
}

// Round 12
// 275.644 us; speedup vs baseline: 1.2591x; 1.2591x over previous
//
#include <hip/hip_runtime.h>
#include <cmath>

#define HN 1024
#define NCH 12
#define PI2 6.28318530717958647692f

// ---------- complex helpers ----------
__device__ __forceinline__ float2 cmul(float2 a, float2 b) {
  return make_float2(a.x * b.x - a.y * b.y, a.x * b.y + a.y * b.x);
}

// reverse 5 base-4 digits of a 10-bit index (involution)
__device__ __forceinline__ int drev(int k) {
  int r = 0;
#pragma unroll
  for (int i = 0; i < 5; ++i) { r = (r << 2) | (k & 3); k >>= 2; }
  return r;
}

// Tile-blocked layout for the A intermediate: element (nc, h, w) lives at
// ((nc*64 + w/16) * 1024 + h) * 16 + (w%16).  Column kernels (fixed w-tile)
// see a fully SEQUENTIAL 128 KB stream; row kernels scatter/gather 128 B
// chunks whose DRAM-row locality is provided by adjacent blocks (adjacent
// rows -> adjacent 128 B of the same tile).
__device__ __forceinline__ size_t AIDX(int nc, int h, int w) {
  return ((((size_t)nc << 6) | (unsigned)(w >> 4)) << 14) + ((size_t)h << 4) + (w & 15);
}

// row-kernel LDS swizzle: pad every 16 elements
#define RIDX(h) ((h) + ((h) >> 4))
// padded twiddle index
#define TIDX(i) ((i) + ((i) >> 4))
// column-exchange buffer: 512 rows x 16 cols, stride 17
#define EIDX(h, c) ((h) * 17 + (c))

// ---------- radix-4 DIF butterfly (row kernels, unpadded tw) ----------
template <bool INV>
__device__ __forceinline__ void bf4(float2& a0, float2& a1, float2& a2, float2& a3,
                                    const float2* tw, int e) {
  float2 t0 = make_float2(a0.x + a2.x, a0.y + a2.y);
  float2 t1 = make_float2(a0.x - a2.x, a0.y - a2.y);
  float2 t2 = make_float2(a1.x + a3.x, a1.y + a3.y);
  float2 t3 = make_float2(a1.x - a3.x, a1.y - a3.y);
  float2 b0 = make_float2(t0.x + t2.x, t0.y + t2.y);
  float2 b2 = make_float2(t0.x - t2.x, t0.y - t2.y);
  float2 b1, b3;
  if (!INV) {
    b1 = make_float2(t1.x + t3.y, t1.y - t3.x);
    b3 = make_float2(t1.x - t3.y, t1.y + t3.x);
  } else {
    b1 = make_float2(t1.x - t3.y, t1.y + t3.x);
    b3 = make_float2(t1.x + t3.y, t1.y - t3.x);
  }
  float2 w1 = tw[e], w2 = tw[2 * e], w3 = tw[3 * e];
  if (INV) { w1.y = -w1.y; w2.y = -w2.y; w3.y = -w3.y; }
  a0 = b0;
  a1 = cmul(b1, w1);
  a2 = cmul(b2, w2);
  a3 = cmul(b3, w3);
}

// ---------- radix-4 DIF butterfly (column kernels, TIDX-padded tw) ----------
template <bool INV>
__device__ __forceinline__ void bf4t(float2& a0, float2& a1, float2& a2, float2& a3,
                                     const float2* tw, int e) {
  float2 t0 = make_float2(a0.x + a2.x, a0.y + a2.y);
  float2 t1 = make_float2(a0.x - a2.x, a0.y - a2.y);
  float2 t2 = make_float2(a1.x + a3.x, a1.y + a3.y);
  float2 t3 = make_float2(a1.x - a3.x, a1.y - a3.y);
  float2 b0 = make_float2(t0.x + t2.x, t0.y + t2.y);
  float2 b2 = make_float2(t0.x - t2.x, t0.y - t2.y);
  float2 b1, b3;
  if (!INV) {
    b1 = make_float2(t1.x + t3.y, t1.y - t3.x);
    b3 = make_float2(t1.x - t3.y, t1.y + t3.x);
  } else {
    b1 = make_float2(t1.x - t3.y, t1.y + t3.x);
    b3 = make_float2(t1.x + t3.y, t1.y - t3.x);
  }
  float2 w1 = tw[TIDX(e)], w2 = tw[TIDX(2 * e)], w3 = tw[TIDX(3 * e)];
  if (INV) { w1.y = -w1.y; w2.y = -w2.y; w3.y = -w3.y; }
  a0 = b0;
  a1 = cmul(b1, w1);
  a2 = cmul(b2, w2);
  a3 = cmul(b3, w3);
}

__device__ __forceinline__ void tw_init(float2* tw, int t, int nthr) {
  for (int i = t; i < 768; i += nthr) {
    float s, c;
    sincosf((float)i * (PI2 / 1024.f), &s, &c);
    tw[i] = make_float2(c, -s);
  }
}

__device__ __forceinline__ void tw_init_p(float2* tw, int t, int nthr) {
  for (int i = t; i < 768; i += nthr) {
    float s, c;
    sincosf((float)i * (PI2 / 1024.f), &s, &c);
    tw[TIDX(i)] = make_float2(c, -s);
  }
}

// 1024-pt radix-4 DIF FFT, one row per block, 256 threads.
template <bool INV>
__device__ __forceinline__ void fft_row(float2* x, const float2* tw, int t) {
#pragma unroll
  for (int ld = 8; ld >= 0; ld -= 2) {
    __syncthreads();
    const int d = 1 << ld;
    int j = t & (d - 1);
    int p0 = ((t >> ld) << (ld + 2)) | j;
    float2 a0 = x[RIDX(p0)];
    float2 a1 = x[RIDX(p0 + d)];
    float2 a2 = x[RIDX(p0 + 2 * d)];
    float2 a3 = x[RIDX(p0 + 3 * d)];
    bf4<INV>(a0, a1, a2, a3, tw, j << (8 - ld));
    x[RIDX(p0)] = a0;
    x[RIDX(p0 + d)] = a1;
    x[RIDX(p0 + 2 * d)] = a2;
    x[RIDX(p0 + 3 * d)] = a3;
  }
  __syncthreads();
}

// ---------------------------------------------------------------------------
// Register-resident 1024-pt column FFT (16 cols/block, 1024 thr) — verified.
// ---------------------------------------------------------------------------
template <bool INV>
__device__ __forceinline__ void colfft16(float2 (&r)[16], float2 (&q)[16],
                                         float2* ex, const float2* tw,
                                         int u, int c) {
  const int j2 = u & 3, B = u >> 2;
#pragma unroll
  for (int s = 0; s < 4; ++s)
    bf4t<INV>(r[s], r[s + 4], r[s + 8], r[s + 12], tw, u + (s << 6));
#pragma unroll
  for (int g = 0; g < 4; ++g)
    bf4t<INV>(r[4 * g], r[4 * g + 1], r[4 * g + 2], r[4 * g + 3], tw, u << 2);
#pragma unroll
  for (int it = 0; it < 8; ++it)
    ex[EIDX(u + (it << 6), c)] = r[it];
  __syncthreads();
  if (u < 32) {
#pragma unroll
    for (int m = 0; m < 16; ++m) {
      int hl = (B << 6) + j2 + ((m & 3) << 2) + ((m >> 2) << 4);
      q[m] = ex[EIDX(hl, c)];
    }
  }
  __syncthreads();
#pragma unroll
  for (int it = 8; it < 16; ++it)
    ex[EIDX(u + (it << 6) - 512, c)] = r[it];
  __syncthreads();
  if (u >= 32) {
#pragma unroll
    for (int m = 0; m < 16; ++m) {
      int hl = ((B - 8) << 6) + j2 + ((m & 3) << 2) + ((m >> 2) << 4);
      q[m] = ex[EIDX(hl, c)];
    }
  }
#pragma unroll
  for (int a = 0; a < 4; ++a)
    bf4t<INV>(q[a], q[4 + a], q[8 + a], q[12 + a], tw, (j2 + 4 * a) << 4);
#pragma unroll
  for (int b_ = 0; b_ < 4; ++b_)
    bf4t<INV>(q[4 * b_], q[4 * b_ + 1], q[4 * b_ + 2], q[4 * b_ + 3], tw, j2 << 6);
#pragma unroll
  for (int m = 0; m < 16; ++m) {
    float2 v = q[m];
    float2 p;
    p.x = __shfl_xor(v.x, 32);
    p.y = __shfl_xor(v.y, 32);
    float2 w;
    if (j2 & 2) { w.x = p.x - v.x; w.y = p.y - v.y; }
    else        { w.x = v.x + p.x; w.y = v.y + p.y; }
    float2 p2;
    p2.x = __shfl_xor(w.x, 16);
    p2.y = __shfl_xor(w.y, 16);
    float2 o;
    if (j2 == 0)      { o = make_float2(w.x + p2.x, w.y + p2.y); }
    else if (j2 == 1) { o = make_float2(p2.x - w.x, p2.y - w.y); }
    else if (j2 == 2) { o = INV ? make_float2(w.x - p2.y, w.y + p2.x)
                                : make_float2(w.x + p2.y, w.y - p2.x); }
    else              { o = INV ? make_float2(p2.x + w.y, p2.y - w.x)
                                : make_float2(p2.x - w.y, p2.y + w.x); }
    q[m] = o;
  }
}

// ---------------- K3a: invW partial = sum of F2k over sf x sf blocks (runs FIRST) ----------------
__global__ __launch_bounds__(256) void k3a_w(const float2* __restrict__ F2k,
                                             float2* __restrict__ w2) {
  int idx = blockIdx.x * 256 + threadIdx.x;
  int j = idx & 255, i = (idx >> 8) & 255, nc = idx >> 16;
  size_t base = (size_t)nc * HN * HN;
  float wx = 0.f, wy = 0.f;
#pragma unroll
  for (int s1 = 0; s1 < 4; ++s1) {
#pragma unroll
    for (int s2 = 0; s2 < 4; ++s2) {
      float2 f2 = F2k[base + (size_t)((s1 << 8) + i) * HN + ((s2 << 8) + j)];
      wx += f2.x;
      wy += f2.y;
    }
  }
  w2[idx] = make_float2(wx, wy);
}

// ---------------- K1: row FFT of alpha*z -> A (blocked-layout store) ----------------
__global__ __launch_bounds__(256) void k1_rowfft(const float* __restrict__ z,
                                                 const float* __restrict__ alpha,
                                                 float2* __restrict__ A) {
  __shared__ float2 x[1088];
  __shared__ float2 tw[768];
  const int t = threadIdx.x;
  const int row = blockIdx.x, nc = blockIdx.y;
  tw_init(tw, t, 256);
  const float al = alpha[nc / 3];
  const float4* zr4 = (const float4*)(z + ((size_t)nc * HN + row) * HN);
  {
    float4 v = zr4[t];
    int h = t << 2;
    x[RIDX(h + 0)] = make_float2(v.x * al, 0.f);
    x[RIDX(h + 1)] = make_float2(v.y * al, 0.f);
    x[RIDX(h + 2)] = make_float2(v.z * al, 0.f);
    x[RIDX(h + 3)] = make_float2(v.w * al, 0.f);
  }
  fft_row<false>(x, tw, t);
#pragma unroll
  for (int half = 0; half < 2; ++half) {
    int k0 = (half << 9) | (t << 1);            // even logical k
    float2 a = x[RIDX(drev(k0))];
    float2 b = x[RIDX(drev(k0 | 1))];
    *(float4*)&A[AIDX(nc, row, k0)] = make_float4(a.x, a.y, b.x, b.y);
  }
}

// ---------------- K2: col FFT in-place on A (sequential), + FkCFy -> FR ----------------
__global__ __launch_bounds__(1024, 4) void k2_colfft(float2* __restrict__ A,
                                                     const float2* __restrict__ FkCFy) {
  __shared__ float2 ex[8704];
  __shared__ float2 tw[816];
  const int t = threadIdx.x;
  const int c = t & 15, u = t >> 4;
  const int w0 = blockIdx.x << 4;
  const int nc = blockIdx.y;
  const size_t base = (size_t)nc * HN * HN;
  const size_t tb = AIDX(nc, 0, w0);            // tile base; AIDX(nc,h,w0+c) = tb + h*16 + c
  float2 r[16], q[16];
#pragma unroll
  for (int it = 0; it < 16; ++it) {
    int h = u + (it << 6);
    r[it] = A[tb + ((size_t)h << 4) + c];
  }
  tw_init_p(tw, t, 1024);
  __syncthreads();
  colfft16<false>(r, q, ex, tw, u, c);
  const int j2 = u & 3, B = u >> 2;
  const int f = ((j2 & 1) << 1) | (j2 >> 1);
#pragma unroll
  for (int m = 0; m < 16; ++m) {
    int k = (f << 8) | ((m & 3) << 6) | ((m >> 2) << 4) | ((B & 3) << 2) | (B >> 2);
    float2 fy = FkCFy[base + (size_t)k * HN + w0 + c];
    A[tb + ((size_t)k << 4) + c] = make_float2(q[m].x + fy.x, q[m].y + fy.y);
  }
}

// ---------------- K3b: FBR = mean(Fk*FR); invWBR = FBR / (invW + alpha) ----------------
__global__ __launch_bounds__(256) void k3b_iw(const float2* __restrict__ A,
                                              const float2* __restrict__ Fk,
                                              const float2* __restrict__ w2,
                                              const float* __restrict__ alpha,
                                              float2* __restrict__ iw) {
  int idx = blockIdx.x * 256 + threadIdx.x;
  int j = idx & 255, i = (idx >> 8) & 255, nc = idx >> 16;
  size_t base = (size_t)nc * HN * HN;
  float sx = 0.f, sy = 0.f;
#pragma unroll
  for (int s1 = 0; s1 < 4; ++s1) {
#pragma unroll
    for (int s2 = 0; s2 < 4; ++s2) {
      int h = (s1 << 8) + i, w = (s2 << 8) + j;
      float2 fr = A[AIDX(nc, h, w)];
      float2 fk = Fk[base + (size_t)h * HN + w];
      sx += fk.x * fr.x - fk.y * fr.y;
      sy += fk.x * fr.y + fk.y * fr.x;
    }
  }
  const float al = alpha[nc / 3];
  float2 wv = w2[idx];
  float dx = wv.x * 0.0625f + al, dy = wv.y * 0.0625f;  // invW + alpha (real part)
  float nx = sx * 0.0625f, ny = sy * 0.0625f;           // FBR
  float inv = 1.0f / (dx * dx + dy * dy);
  iw[idx] = make_float2((nx * dx + ny * dy) * inv, (ny * dx - nx * dy) * inv);
}

// ---------------- K4: FX = (FR - FkC*invWBR)/alpha, inverse col FFT in-place ----------------
__global__ __launch_bounds__(1024, 4) void k4_colifft(float2* __restrict__ A,
                                                      const float2* __restrict__ FkC,
                                                      const float2* __restrict__ iw,
                                                      const float* __restrict__ alpha) {
  __shared__ float2 ex[8704];
  __shared__ float2 tw[816];
  const int t = threadIdx.x;
  const int c = t & 15, u = t >> 4;
  const int w0 = blockIdx.x << 4;
  const int nc = blockIdx.y;
  const float al = alpha[nc / 3];
  const float ra = 1.0f / al;
  const size_t base = (size_t)nc * HN * HN;
  const size_t tb = AIDX(nc, 0, w0);
  const int jcol = (w0 + c) & 255;
  const float2* iwp = iw + ((size_t)nc << 16);
  float2 r[16], q[16];
#pragma unroll
  for (int it = 0; it < 16; ++it) {
    int h = u + (it << 6);
    float2 fr = A[tb + ((size_t)h << 4) + c];
    float2 fc = FkC[base + (size_t)h * HN + w0 + c];
    float2 w = iwp[((h & 255) << 8) | jcol];
    float2 p = cmul(fc, w);
    r[it] = make_float2((fr.x - p.x) * ra, (fr.y - p.y) * ra);
  }
  tw_init_p(tw, t, 1024);
  __syncthreads();
  colfft16<true>(r, q, ex, tw, u, c);
  const int j2 = u & 3, B = u >> 2;
  const int f = ((j2 & 1) << 1) | (j2 >> 1);
#pragma unroll
  for (int m = 0; m < 16; ++m) {
    int k = (f << 8) | ((m & 3) << 6) | ((m >> 2) << 4) | ((B & 3) << 2) | (B >> 2);
    A[tb + ((size_t)k << 4) + c] = q[m];
  }
}

// ---------------- K5: inverse row FFT -> real * 1/(H*W) -> out (blocked-layout load) ----------------
__global__ __launch_bounds__(256) void k5_rowifft(const float2* __restrict__ A,
                                                  float* __restrict__ out) {
  __shared__ float2 x[1088];
  __shared__ float2 tw[768];
  const int t = threadIdx.x;
  const int row = blockIdx.x, nc = blockIdx.y;
  tw_init(tw, t, 256);
#pragma unroll
  for (int half = 0; half < 2; ++half) {
    int h0 = (half << 9) | (t << 1);            // even logical h
    float4 v = *(const float4*)&A[AIDX(nc, row, h0)];
    x[RIDX(h0)] = make_float2(v.x, v.y);
    x[RIDX(h0 | 1)] = make_float2(v.z, v.w);
  }
  fft_row<true>(x, tw, t);
  float4* outr4 = (float4*)(out + ((size_t)nc * HN + row) * HN);
  const float sc = 1.0f / (1024.0f * 1024.0f);
  {
    int k = t << 2;
    float4 o;
    o.x = x[RIDX(drev(k + 0))].x * sc;
    o.y = x[RIDX(drev(k + 1))].x * sc;
    o.z = x[RIDX(drev(k + 2))].x * sc;
    o.w = x[RIDX(drev(k + 3))].x * sc;
    outr4[t] = o;
  }
}

extern "C" void kernel_launch(void* const* d_in, const int* in_sizes, int n_in,
                              void* d_out, int out_size, void* d_ws, size_t ws_size,
                              hipStream_t stream) {
  const float*  z      = (const float*)d_in[0];
  const float2* Fk     = (const float2*)d_in[1];
  const float2* FkC    = (const float2*)d_in[2];
  const float2* F2k    = (const float2*)d_in[3];
  const float2* FkCFy  = (const float2*)d_in[4];
  const float*  alpha  = (const float*)d_in[5];
  (void)in_sizes; (void)n_in; (void)out_size; (void)ws_size;

  // workspace: A 96MB (blocked) | iw 6MB | w2 6MB
  float2* A  = (float2*)d_ws;
  float2* iw = A + (size_t)NCH * HN * HN;
  float2* w2 = iw + (size_t)NCH * 256 * 256;
  float*  out = (float*)d_out;

  // k3a first: its F2k stream must not sit between k2's FR-write and k4's FR-read
  k3a_w<<<dim3(NCH * 256), dim3(256), 0, stream>>>(F2k, w2);
  k1_rowfft<<<dim3(HN, NCH), dim3(256), 0, stream>>>(z, alpha, A);
  k2_colfft<<<dim3(HN / 16, NCH), dim3(1024), 0, stream>>>(A, FkCFy);
  k3b_iw<<<dim3(NCH * 256), dim3(256), 0, stream>>>(A, Fk, w2, alpha, iw);
  k4_colifft<<<dim3(HN / 16, NCH), dim3(1024), 0, stream>>>(A, FkC, iw, alpha);
  k5_rowifft<<<dim3(HN, NCH), dim3(256), 0, stream>>>(A, out);
}